// Round 18
// baseline (134.381 us; speedup 1.0000x reference)
//
#include <hip/hip_runtime.h>

typedef __bf16 bf16;
typedef __attribute__((ext_vector_type(8))) __bf16 bf16x8;
typedef __attribute__((ext_vector_type(4))) float f32x4;
typedef __attribute__((ext_vector_type(16))) float f32x16;
typedef unsigned int u32;
typedef __attribute__((ext_vector_type(2))) unsigned int u32x2;
typedef __attribute__((ext_vector_type(4))) unsigned int u32x4;

#define SEQ 2048
#define EMB 1024
#define NH  16
#define DH  64

// ---------------- fused prep: x->bf16 conv + Wqkv permuted transpose + Wproj transpose ----
__global__ __launch_bounds__(256) void prep(const float* __restrict__ x, bf16* __restrict__ xb,
                                            const float* __restrict__ Wqkv, bf16* __restrict__ WqkvT,
                                            const float* __restrict__ Wproj, bf16* __restrict__ WprojT) {
    __shared__ float t[32][33];
    int b = blockIdx.x;
    if (b < 2048) {
        int i = b * 256 + threadIdx.x;
        float4 a = ((const float4*)x)[2 * i];
        float4 c = ((const float4*)x)[2 * i + 1];
        bf16x8 o;
        o[0] = (bf16)a.x; o[1] = (bf16)a.y; o[2] = (bf16)a.z; o[3] = (bf16)a.w;
        o[4] = (bf16)c.x; o[5] = (bf16)c.y; o[6] = (bf16)c.z; o[7] = (bf16)c.w;
        ((bf16x8*)xb)[i] = o;
        return;
    }
    int tx = threadIdx.x & 31, ty = threadIdx.x >> 5;
    if (b < 5120) {
        int flat = b - 2048;
        int c0 = (flat % 96) * 32, r0 = (flat / 96) * 32;
#pragma unroll
        for (int s = 0; s < 4; s++) {
            int row = ty + s * 8;
            t[row][tx] = Wqkv[(size_t)(r0 + row) * 3072 + c0 + tx];
        }
        __syncthreads();
#pragma unroll
        for (int s = 0; s < 4; s++) {
            int row = ty + s * 8;
            int corig = c0 + row;
            int hh = corig / 192;
            int rem = corig - hh * 192;
            int dd = rem / 3;
            int which = rem - dd * 3;
            int colp = which * 1024 + hh * 64 + dd;
            WqkvT[(size_t)colp * EMB + r0 + tx] = (bf16)t[tx][row];
        }
    } else {
        int flat = b - 5120;
        int c0 = (flat % 32) * 32, r0 = (flat / 32) * 32;
#pragma unroll
        for (int s = 0; s < 4; s++) {
            int row = ty + s * 8;
            t[row][tx] = Wproj[(size_t)(r0 + row) * EMB + c0 + tx];
        }
        __syncthreads();
#pragma unroll
        for (int s = 0; s < 4; s++) {
            int row = ty + s * 8;
            WprojT[(size_t)(c0 + row) * EMB + r0 + tx] = (bf16)t[tx][row];
        }
    }
}

// ---------------- GEMM core (128x128, BK=32, TRIPLE-buffered, counted vmcnt) ----------------

#define BM 128
#define BN 128
#define BK 32

__device__ __forceinline__ void gload16(const bf16* g, bf16* l) {
    __builtin_amdgcn_global_load_lds((__attribute__((address_space(1))) void*)(void*)g,
                                     (__attribute__((address_space(3))) void*)l, 16, 0, 0);
}

__device__ __forceinline__ void stage_tile(const bf16* src, int ld, int row0, int k0,
                                           bf16* lds, int wave, int lane) {
#pragma unroll
    for (int c = 0; c < 2; c++) {
        int chunk = wave + 4 * c;
        int row = chunk * 16 + (lane >> 2);
        int slot = (lane & 3) ^ ((lane >> 2) & 3);
        const bf16* g = src + (size_t)(row0 + row) * ld + k0 + slot * 8;
        gload16(g, lds + chunk * 512);
    }
}

__device__ __forceinline__ bf16x8 frag(const bf16* lds, int row, int s) {
    int slot = s ^ (row & 3);
    return *(const bf16x8*)&lds[row * BK + slot * 8];
}

__device__ __forceinline__ void gemm_mainloop(const bf16* A, const bf16* Bt, int Kdim,
                                              int m0, int n0, bf16* As, bf16* Bs,
                                              int wave, int lane, int wr, int wc,
                                              f32x4 acc[4][4]) {
    const int iters = Kdim / BK;
    stage_tile(A, Kdim, m0, 0, As, wave, lane);
    stage_tile(Bt, Kdim, n0, 0, Bs, wave, lane);
    stage_tile(A, Kdim, m0, BK, As + BM * BK, wave, lane);
    stage_tile(Bt, Kdim, n0, BK, Bs + BM * BK, wave, lane);
    asm volatile("s_waitcnt vmcnt(4)" ::: "memory");   // tile 0 landed
    __builtin_amdgcn_s_barrier();

    for (int it = 0; it < iters; ++it) {
        int cur = it % 3;
        bool more = (it + 2 < iters);
        if (more) {
            int nxt = (it + 2) % 3;
            stage_tile(A, Kdim, m0, (it + 2) * BK, As + nxt * BM * BK, wave, lane);
            stage_tile(Bt, Kdim, n0, (it + 2) * BK, Bs + nxt * BM * BK, wave, lane);
        }
        const bf16* as = As + cur * BM * BK;
        const bf16* bs = Bs + cur * BM * BK;
        int s = lane >> 4;
        bf16x8 a[4], b[4];
#pragma unroll
        for (int i = 0; i < 4; i++)
            a[i] = frag(as, wr * 64 + i * 16 + (lane & 15), s);
#pragma unroll
        for (int j = 0; j < 4; j++)
            b[j] = frag(bs, wc * 64 + j * 16 + (lane & 15), s);
#pragma unroll
        for (int i = 0; i < 4; i++)
#pragma unroll
            for (int j = 0; j < 4; j++)
                acc[i][j] = __builtin_amdgcn_mfma_f32_16x16x32_bf16(a[i], b[j], acc[i][j], 0, 0, 0);
        if (more)
            asm volatile("s_waitcnt vmcnt(4)" ::: "memory");
        else
            asm volatile("s_waitcnt vmcnt(0)" ::: "memory");
        __builtin_amdgcn_s_barrier();
    }
}

// QKV projection with permuted weights (layouts verified R6-R13).
__global__ __launch_bounds__(256) void gemm_qkv(const bf16* __restrict__ A,
                                                const bf16* __restrict__ Bt,
                                                const float* __restrict__ bias,
                                                bf16* __restrict__ Qb, bf16* __restrict__ Kb,
                                                bf16* __restrict__ Vt) {
    __shared__ alignas(16) bf16 smem[6 * BM * BK];
    bf16* As = smem;
    bf16* Bs = smem + 3 * BM * BK;
    int wave = threadIdx.x >> 6, lane = threadIdx.x & 63;
    int wr = wave >> 1, wc = wave & 1;

    int flat = blockIdx.y * 24 + blockIdx.x;
    int swz = (flat & 7) * 96 + (flat >> 3);
    int n0 = (swz % 24) * BN;
    int m0 = (swz / 24) * BM;

    f32x4 acc[4][4] = {};
    gemm_mainloop(A, Bt, EMB, m0, n0, As, Bs, wave, lane, wr, wc, acc);

    int which = n0 >> 10;
    bool isV = (which == 2);
    char* tile = (char*)smem;
    __builtin_amdgcn_s_barrier();

#pragma unroll
    for (int i = 0; i < 4; i++) {
#pragma unroll
        for (int j = 0; j < 4; j++) {
            int c = wc * 64 + j * 16 + (lane & 15);
            int hh = ((n0 + c) >> 6) & 15;
            int dd = c & 63;
            float bv = bias[hh * 192 + dd * 3 + which];
#pragma unroll
            for (int r = 0; r < 4; r++) {
                int rowL = wr * 64 + i * 16 + 4 * (lane >> 4) + r;
                float v = acc[i][j][r] + bv;
                if (which == 0) v *= 0.03125f;   // 1/sqrt(1024)
                int byte;
                if (!isV) byte = rowL * 256 + ((c * 2) ^ ((rowL & 7) << 4));
                else      byte = c * 256 + ((((rowL >> 3) ^ (c & 15)) << 4) + (rowL & 7) * 2);
                *(bf16*)(tile + byte) = (bf16)v;
            }
        }
    }
    __builtin_amdgcn_s_barrier();

    int tid = threadIdx.x;
    if (which == 0) {
#pragma unroll
        for (int k = 0; k < 8; k++) {
            int f = k * 256 + tid;
            int rowL = f >> 4, ch = f & 15;
            bf16x8 val = *(const bf16x8*)(tile + rowL * 256 + ((ch ^ (rowL & 7)) << 4));
            int grow = m0 + rowL;
            int bb = grow >> 11, npos = grow & 2047;
            int cbase = ch * 8;
            int hh = ((n0 + cbase) >> 6) & 15;
            int d0 = cbase & 63;
            *(bf16x8*)(Qb + (((size_t)bb * NH + hh) * SEQ + npos) * DH + d0) = val;
        }
    } else if (which == 1) {
#pragma unroll
        for (int k = 0; k < 8; k++) {
            int f = k * 256 + tid;
            int rowL = f >> 4, ch = f & 15;
            bf16x8 val = *(const bf16x8*)(tile + rowL * 256 + ((ch ^ (rowL & 7)) << 4));
            int grow = m0 + rowL;
            int bb = grow >> 11, npos = grow & 2047;
            int cbase = ch * 8;
            int hh = ((n0 + cbase) >> 6) & 15;
            int d0 = cbase & 63;
            size_t base = ((size_t)bb * NH + hh) * (SEQ * DH) + (size_t)(npos >> 6) * 4096;
            int chunk = ((npos >> 5) & 1) * 8 + (d0 >> 4) * 2 + ((d0 >> 3) & 1);
            *(bf16x8*)(Kb + base + chunk * 256 + (npos & 31) * 8) = val;
        }
    } else {
#pragma unroll
        for (int k = 0; k < 8; k++) {
            int f = k * 256 + tid;
            int cL = f >> 4, g = f & 15;
            bf16x8 val = *(const bf16x8*)(tile + cL * 256 + ((g ^ (cL & 15)) << 4));
            int grow = m0 + g * 8;
            int bb = grow >> 11, nn = grow & 2047;
            int hh = ((n0 + cL) >> 6) & 15;
            int d = cL & 63;
            int tIdx = nn >> 6;
            int mb = nn & 63;
            int mc = mb >> 4, half = (mb >> 3) & 1;
            char* base = (char*)Vt +
                         (((size_t)bb * NH + hh) * (SEQ * DH) + (size_t)tIdx * 4096) * 2;
            u32x4 vv = __builtin_bit_cast(u32x4, val);
            u32x2 lo = {vv.x, vv.y};
            u32x2 hi = {vv.z, vv.w};
            int off = ((d >> 5) * 4 + mc) * 1024 + (d & 31) * 16 + half * 8;
            *(u32x2*)(base + off) = lo;
            *(u32x2*)(base + off + 512) = hi;
        }
    }
}

// proj: fp32 out + bias
__global__ __launch_bounds__(256) void gemm_proj(const bf16* __restrict__ A,
                                                 const bf16* __restrict__ Bt,
                                                 const float* __restrict__ bias,
                                                 float* __restrict__ C) {
    __shared__ alignas(16) bf16 smem[6 * BM * BK];
    bf16* As = smem;
    bf16* Bs = smem + 3 * BM * BK;
    int wave = threadIdx.x >> 6, lane = threadIdx.x & 63;
    int wr = wave >> 1, wc = wave & 1;
    int m0 = blockIdx.y * BM, n0 = blockIdx.x * BN;
    f32x4 acc[4][4] = {};
    gemm_mainloop(A, Bt, EMB, m0, n0, As, Bs, wave, lane, wr, wc, acc);

    int m_base = m0 + wr * 64;
    int n_base = n0 + wc * 64;
#pragma unroll
    for (int i = 0; i < 4; i++) {
#pragma unroll
        for (int j = 0; j < 4; j++) {
            int col = n_base + j * 16 + (lane & 15);
            float bv = bias[col];
#pragma unroll
            for (int r = 0; r < 4; r++) {
                int row = m_base + i * 16 + 4 * (lane >> 4) + r;
                C[(size_t)row * EMB + col] = acc[i][j][r] + bv;
            }
        }
    }
}

// ---------------- attention: KV-split (grid 1024) + T-group interleave ----------------
// fl>>9 = kv-half; each block: 4 waves x 32 q, 8 iters KVBLK=128 over its half.
// launch_bounds(256,3): VGPR cap ~85, target 3 blocks/CU co-residency.
// Inner loop = R17's interleave (QK -> exp -> PV per T-group, w[8] live only).
// K in LDS dbuf (32KB); V direct from global (chunked, L2). Partial O + lsum out.

__device__ __forceinline__ void stage16k(const bf16* src, bf16* lds, int wave, int lane) {
#pragma unroll
    for (int i = 0; i < 4; i++) {
        int c = wave * 4 + i;
        gload16(src + c * 512 + lane * 8, lds + c * 512);
    }
}

__device__ __forceinline__ u32 pack_bf16(float lo, float hi) {
    unsigned short a = __builtin_bit_cast(unsigned short, (bf16)lo);
    unsigned short b = __builtin_bit_cast(unsigned short, (bf16)hi);
    return (u32)a | ((u32)b << 16);
}

__global__ __launch_bounds__(256, 3) void attn(const bf16* __restrict__ Q,
                                               const bf16* __restrict__ K,
                                               const bf16* __restrict__ Vt,
                                               bf16* __restrict__ Op,
                                               float* __restrict__ lsumP) {
    int fl = blockIdx.x;
    int half = fl >> 9;
    int flat = fl & 511;
    int swz = (flat & 7) * 64 + (flat >> 3);
    int bh = swz >> 4;
    int qb = swz & 15;

    int wave = threadIdx.x >> 6, lane = threadIdx.x & 63;
    int l31 = lane & 31, h = lane >> 5;
    int qw0 = qb * 128 + wave * 32;
    const bf16* Qg = Q + (size_t)bh * SEQ * DH;
    const bf16* Kg = K + (size_t)bh * SEQ * DH + half * 65536;
    const bf16* Vg = Vt + (size_t)bh * SEQ * DH + half * 65536;

    __shared__ alignas(16) bf16 Ks[2][8192];   // 32 KB

    bf16x8 qf[4];
#pragma unroll
    for (int ks = 0; ks < 4; ks++)
        qf[ks] = *(const bf16x8*)(Qg + (size_t)(qw0 + l31) * DH + ks * 16 + h * 8);

    f32x16 Oc[2] = {};
    float lsum = 0.f;

    stage16k(Kg, &Ks[0][0], wave, lane);
    asm volatile("s_waitcnt vmcnt(0)" ::: "memory");
    __builtin_amdgcn_s_barrier();

    int cur = 0;
    const int NIT = 8;   // 1024 kv / 128
    for (int it = 0; it < NIT; ++it) {
        if (it + 1 < NIT) {
            stage16k(Kg + (size_t)(it + 1) * 8192, &Ks[cur ^ 1][0], wave, lane);
        }
        const char* kc = (const char*)&Ks[cur][0];
        const bf16* vgi = Vg + (size_t)it * 8192;

        float part[4];
#pragma unroll
        for (int T = 0; T < 4; T++) {
            // QK^T for row-group T
            bf16x8 kf[4];
#pragma unroll
            for (int ks = 0; ks < 4; ks++)
                kf[ks] = *(const bf16x8*)(kc + (((T * 4 + ks) * 2 + h) << 9) + l31 * 16);
            f32x16 st = {};
#pragma unroll
            for (int ks = 0; ks < 4; ks++)
                st = __builtin_amdgcn_mfma_f32_32x32x16_bf16(kf[ks], qf[ks], st, 0, 0, 0);

            // exp + pack (this group's w only)
            u32 w[8];
            float acc = 0.f;
#pragma unroll
            for (int p = 0; p < 8; p++) {
                float p0 = __expf(st[2 * p]);
                float p1 = __expf(st[2 * p + 1]);
                acc += p0 + p1;
                w[p] = pack_bf16(p0, p1);
            }
            part[T] = acc;

            // PV MFMAs consuming w: mg = T>>1, mc in {2*(T&1), 2*(T&1)+1}
            int mg = T >> 1;
#pragma unroll
            for (int dt = 0; dt < 2; dt++)
#pragma unroll
                for (int mi = 0; mi < 2; mi++) {
                    int mc = 2 * (T & 1) + mi;
                    bf16x8 vf = *(const bf16x8*)(vgi + mg * 4096 +
                                                 ((dt * 4 + mc) * 2 + h) * 256 + l31 * 8);
                    u32x4 pw = {w[4 * mi + 0], w[4 * mi + 1], w[4 * mi + 2], w[4 * mi + 3]};
                    bf16x8 pa = __builtin_bit_cast(bf16x8, pw);
                    Oc[dt] = __builtin_amdgcn_mfma_f32_32x32x16_bf16(pa, vf, Oc[dt], 0, 0, 0);
                }
        }
        lsum += (part[0] + part[1]) + (part[2] + part[3]);

        asm volatile("s_waitcnt vmcnt(0)" ::: "memory");
        __builtin_amdgcn_s_barrier();
        cur ^= 1;
    }

    // ---- partial epilogue: raw O (bf16) + per-q lsum ----
    float ls = lsum + __shfl_xor(lsum, 32);
    if (h == 0)
        lsumP[((size_t)half * 32 + bh) * SEQ + qw0 + l31] = ls;

    bf16* dst = Op + (((size_t)half * 32 + bh) * SEQ + qw0) * DH;
#pragma unroll
    for (int reg = 0; reg < 16; reg++) {
        int qlocal = (reg & 3) + 8 * (reg >> 2) + 4 * h;
#pragma unroll
        for (int dt = 0; dt < 2; dt++)
            dst[(size_t)qlocal * DH + dt * 32 + l31] = (bf16)Oc[dt][reg];
    }
}

// combine: O = (O0 + O1) / (ls0 + ls1), write attO [b][n][e] bf16
__global__ __launch_bounds__(256) void attn_combine(const bf16* __restrict__ Op,
                                                    const float* __restrict__ lsumP,
                                                    bf16* __restrict__ O) {
    int g = blockIdx.x * 256 + threadIdx.x;   // 0..524287 groups of 8 elems
    int dg = g & 7;
    int q = (g >> 3) & 2047;
    int bh = g >> 14;
    size_t po = ((size_t)bh * SEQ + q) * DH + dg * 8;
    bf16x8 a = *(const bf16x8*)(Op + po);
    bf16x8 b = *(const bf16x8*)(Op + (size_t)32 * SEQ * DH + po);
    float rinv = 1.0f / (lsumP[(size_t)bh * SEQ + q] + lsumP[(size_t)(32 + bh) * SEQ + q]);
    bf16x8 o;
#pragma unroll
    for (int j = 0; j < 8; j++)
        o[j] = (bf16)(((float)a[j] + (float)b[j]) * rinv);
    int bb = bh >> 4, hh = bh & 15;
    *(bf16x8*)(O + ((size_t)bb * SEQ + q) * EMB + hh * DH + dg * 8) = o;
}

// ---------------- launch ----------------

extern "C" void kernel_launch(void* const* d_in, const int* in_sizes, int n_in,
                              void* d_out, int out_size, void* d_ws, size_t ws_size,
                              hipStream_t stream) {
    const float* x     = (const float*)d_in[0];
    const float* Wqkv  = (const float*)d_in[1];
    const float* bqkv  = (const float*)d_in[2];
    const float* Wproj = (const float*)d_in[3];
    const float* bproj = (const float*)d_in[4];
    float* out = (float*)d_out;
    char* ws = (char*)d_ws;

    bf16* xb     = (bf16*)(ws + 0);          //  8 MB [4096][1024]
    bf16* attO   = xb;                       //  aliased: xb dead after gemm_qkv
    bf16* WqkvT  = (bf16*)(ws + 8388608);    //  6 MB; dead after gemm_qkv
    float* lsumP = (float*)(ws + 8388608);   //  512 KB partial lsums (aliases dead WqkvT)
    bf16* WprojT = (bf16*)(ws + 14680064);   //  2 MB [1024][1024]
    bf16* Qb     = (bf16*)(ws + 16777216);   //  8 MB [32][2048][64] row-major
    bf16* Kb     = (bf16*)(ws + 25165824);   //  8 MB [32] chunked tiles
    bf16* Vt     = (bf16*)(ws + 33554432);   //  8 MB [32] chunked tiles
    bf16* Op     = (bf16*)d_out;             // 16 MB partial O scratch (fully rewritten;
                                             // final d_out produced by gemm_proj)

    prep<<<6144, 256, 0, stream>>>(x, xb, Wqkv, WqkvT, Wproj, WprojT);
    gemm_qkv<<<dim3(24, 32), 256, 0, stream>>>(xb, WqkvT, bqkv, Qb, Kb, Vt);
    attn<<<1024, 256, 0, stream>>>(Qb, Kb, Vt, Op, lsumP);
    attn_combine<<<2048, 256, 0, stream>>>(Op, lsumP, attO);
    gemm_proj<<<dim3(8, 32), 256, 0, stream>>>(attO, WprojT, bproj, out);
}

// Round 19
// 117.051 us; speedup vs baseline: 1.1481x; 1.1481x over previous
//
#include <hip/hip_runtime.h>

typedef __bf16 bf16;
typedef __attribute__((ext_vector_type(8))) __bf16 bf16x8;
typedef __attribute__((ext_vector_type(4))) float f32x4;
typedef __attribute__((ext_vector_type(16))) float f32x16;
typedef unsigned int u32;
typedef __attribute__((ext_vector_type(2))) unsigned int u32x2;
typedef __attribute__((ext_vector_type(4))) unsigned int u32x4;

#define SEQ 2048
#define EMB 1024
#define NH  16
#define DH  64

// ---------------- fused prep: x->bf16 conv + Wqkv permuted transpose + Wproj transpose ----
__global__ __launch_bounds__(256) void prep(const float* __restrict__ x, bf16* __restrict__ xb,
                                            const float* __restrict__ Wqkv, bf16* __restrict__ WqkvT,
                                            const float* __restrict__ Wproj, bf16* __restrict__ WprojT) {
    __shared__ float t[32][33];
    int b = blockIdx.x;
    if (b < 2048) {
        int i = b * 256 + threadIdx.x;
        float4 a = ((const float4*)x)[2 * i];
        float4 c = ((const float4*)x)[2 * i + 1];
        bf16x8 o;
        o[0] = (bf16)a.x; o[1] = (bf16)a.y; o[2] = (bf16)a.z; o[3] = (bf16)a.w;
        o[4] = (bf16)c.x; o[5] = (bf16)c.y; o[6] = (bf16)c.z; o[7] = (bf16)c.w;
        ((bf16x8*)xb)[i] = o;
        return;
    }
    int tx = threadIdx.x & 31, ty = threadIdx.x >> 5;
    if (b < 5120) {
        int flat = b - 2048;
        int c0 = (flat % 96) * 32, r0 = (flat / 96) * 32;
#pragma unroll
        for (int s = 0; s < 4; s++) {
            int row = ty + s * 8;
            t[row][tx] = Wqkv[(size_t)(r0 + row) * 3072 + c0 + tx];
        }
        __syncthreads();
#pragma unroll
        for (int s = 0; s < 4; s++) {
            int row = ty + s * 8;
            int corig = c0 + row;
            int hh = corig / 192;
            int rem = corig - hh * 192;
            int dd = rem / 3;
            int which = rem - dd * 3;
            int colp = which * 1024 + hh * 64 + dd;
            WqkvT[(size_t)colp * EMB + r0 + tx] = (bf16)t[tx][row];
        }
    } else {
        int flat = b - 5120;
        int c0 = (flat % 32) * 32, r0 = (flat / 32) * 32;
#pragma unroll
        for (int s = 0; s < 4; s++) {
            int row = ty + s * 8;
            t[row][tx] = Wproj[(size_t)(r0 + row) * EMB + c0 + tx];
        }
        __syncthreads();
#pragma unroll
        for (int s = 0; s < 4; s++) {
            int row = ty + s * 8;
            WprojT[(size_t)(c0 + row) * EMB + r0 + tx] = (bf16)t[tx][row];
        }
    }
}

// ---------------- GEMM core (128x128, BK=32, TRIPLE-buffered, counted vmcnt) ----------------

#define BM 128
#define BN 128
#define BK 32

__device__ __forceinline__ void gload16(const bf16* g, bf16* l) {
    __builtin_amdgcn_global_load_lds((__attribute__((address_space(1))) void*)(void*)g,
                                     (__attribute__((address_space(3))) void*)l, 16, 0, 0);
}

__device__ __forceinline__ void stage_tile(const bf16* src, int ld, int row0, int k0,
                                           bf16* lds, int wave, int lane) {
#pragma unroll
    for (int c = 0; c < 2; c++) {
        int chunk = wave + 4 * c;
        int row = chunk * 16 + (lane >> 2);
        int slot = (lane & 3) ^ ((lane >> 2) & 3);
        const bf16* g = src + (size_t)(row0 + row) * ld + k0 + slot * 8;
        gload16(g, lds + chunk * 512);
    }
}

__device__ __forceinline__ bf16x8 frag(const bf16* lds, int row, int s) {
    int slot = s ^ (row & 3);
    return *(const bf16x8*)&lds[row * BK + slot * 8];
}

__device__ __forceinline__ void gemm_mainloop(const bf16* A, const bf16* Bt, int Kdim,
                                              int m0, int n0, bf16* As, bf16* Bs,
                                              int wave, int lane, int wr, int wc,
                                              f32x4 acc[4][4]) {
    const int iters = Kdim / BK;
    stage_tile(A, Kdim, m0, 0, As, wave, lane);
    stage_tile(Bt, Kdim, n0, 0, Bs, wave, lane);
    stage_tile(A, Kdim, m0, BK, As + BM * BK, wave, lane);
    stage_tile(Bt, Kdim, n0, BK, Bs + BM * BK, wave, lane);
    asm volatile("s_waitcnt vmcnt(4)" ::: "memory");   // tile 0 landed
    __builtin_amdgcn_s_barrier();

    for (int it = 0; it < iters; ++it) {
        int cur = it % 3;
        bool more = (it + 2 < iters);
        if (more) {
            int nxt = (it + 2) % 3;
            stage_tile(A, Kdim, m0, (it + 2) * BK, As + nxt * BM * BK, wave, lane);
            stage_tile(Bt, Kdim, n0, (it + 2) * BK, Bs + nxt * BM * BK, wave, lane);
        }
        const bf16* as = As + cur * BM * BK;
        const bf16* bs = Bs + cur * BM * BK;
        int s = lane >> 4;
        bf16x8 a[4], b[4];
#pragma unroll
        for (int i = 0; i < 4; i++)
            a[i] = frag(as, wr * 64 + i * 16 + (lane & 15), s);
#pragma unroll
        for (int j = 0; j < 4; j++)
            b[j] = frag(bs, wc * 64 + j * 16 + (lane & 15), s);
#pragma unroll
        for (int i = 0; i < 4; i++)
#pragma unroll
            for (int j = 0; j < 4; j++)
                acc[i][j] = __builtin_amdgcn_mfma_f32_16x16x32_bf16(a[i], b[j], acc[i][j], 0, 0, 0);
        if (more)
            asm volatile("s_waitcnt vmcnt(4)" ::: "memory");
        else
            asm volatile("s_waitcnt vmcnt(0)" ::: "memory");
        __builtin_amdgcn_s_barrier();
    }
}

// QKV projection with permuted weights (layouts verified R6-R13).
__global__ __launch_bounds__(256) void gemm_qkv(const bf16* __restrict__ A,
                                                const bf16* __restrict__ Bt,
                                                const float* __restrict__ bias,
                                                bf16* __restrict__ Qb, bf16* __restrict__ Kb,
                                                bf16* __restrict__ Vt) {
    __shared__ alignas(16) bf16 smem[6 * BM * BK];
    bf16* As = smem;
    bf16* Bs = smem + 3 * BM * BK;
    int wave = threadIdx.x >> 6, lane = threadIdx.x & 63;
    int wr = wave >> 1, wc = wave & 1;

    int flat = blockIdx.y * 24 + blockIdx.x;
    int swz = (flat & 7) * 96 + (flat >> 3);
    int n0 = (swz % 24) * BN;
    int m0 = (swz / 24) * BM;

    f32x4 acc[4][4] = {};
    gemm_mainloop(A, Bt, EMB, m0, n0, As, Bs, wave, lane, wr, wc, acc);

    int which = n0 >> 10;
    bool isV = (which == 2);
    char* tile = (char*)smem;
    __builtin_amdgcn_s_barrier();

#pragma unroll
    for (int i = 0; i < 4; i++) {
#pragma unroll
        for (int j = 0; j < 4; j++) {
            int c = wc * 64 + j * 16 + (lane & 15);
            int hh = ((n0 + c) >> 6) & 15;
            int dd = c & 63;
            float bv = bias[hh * 192 + dd * 3 + which];
#pragma unroll
            for (int r = 0; r < 4; r++) {
                int rowL = wr * 64 + i * 16 + 4 * (lane >> 4) + r;
                float v = acc[i][j][r] + bv;
                if (which == 0) v *= 0.03125f;   // 1/sqrt(1024)
                int byte;
                if (!isV) byte = rowL * 256 + ((c * 2) ^ ((rowL & 7) << 4));
                else      byte = c * 256 + ((((rowL >> 3) ^ (c & 15)) << 4) + (rowL & 7) * 2);
                *(bf16*)(tile + byte) = (bf16)v;
            }
        }
    }
    __builtin_amdgcn_s_barrier();

    int tid = threadIdx.x;
    if (which == 0) {
#pragma unroll
        for (int k = 0; k < 8; k++) {
            int f = k * 256 + tid;
            int rowL = f >> 4, ch = f & 15;
            bf16x8 val = *(const bf16x8*)(tile + rowL * 256 + ((ch ^ (rowL & 7)) << 4));
            int grow = m0 + rowL;
            int bb = grow >> 11, npos = grow & 2047;
            int cbase = ch * 8;
            int hh = ((n0 + cbase) >> 6) & 15;
            int d0 = cbase & 63;
            *(bf16x8*)(Qb + (((size_t)bb * NH + hh) * SEQ + npos) * DH + d0) = val;
        }
    } else if (which == 1) {
#pragma unroll
        for (int k = 0; k < 8; k++) {
            int f = k * 256 + tid;
            int rowL = f >> 4, ch = f & 15;
            bf16x8 val = *(const bf16x8*)(tile + rowL * 256 + ((ch ^ (rowL & 7)) << 4));
            int grow = m0 + rowL;
            int bb = grow >> 11, npos = grow & 2047;
            int cbase = ch * 8;
            int hh = ((n0 + cbase) >> 6) & 15;
            int d0 = cbase & 63;
            size_t base = ((size_t)bb * NH + hh) * (SEQ * DH) + (size_t)(npos >> 6) * 4096;
            int chunk = ((npos >> 5) & 1) * 8 + (d0 >> 4) * 2 + ((d0 >> 3) & 1);
            *(bf16x8*)(Kb + base + chunk * 256 + (npos & 31) * 8) = val;
        }
    } else {
#pragma unroll
        for (int k = 0; k < 8; k++) {
            int f = k * 256 + tid;
            int cL = f >> 4, g = f & 15;
            bf16x8 val = *(const bf16x8*)(tile + cL * 256 + ((g ^ (cL & 15)) << 4));
            int grow = m0 + g * 8;
            int bb = grow >> 11, nn = grow & 2047;
            int hh = ((n0 + cL) >> 6) & 15;
            int d = cL & 63;
            int tIdx = nn >> 6;
            int mb = nn & 63;
            int mc = mb >> 4, half = (mb >> 3) & 1;
            char* base = (char*)Vt +
                         (((size_t)bb * NH + hh) * (SEQ * DH) + (size_t)tIdx * 4096) * 2;
            u32x4 vv = __builtin_bit_cast(u32x4, val);
            u32x2 lo = {vv.x, vv.y};
            u32x2 hi = {vv.z, vv.w};
            int off = ((d >> 5) * 4 + mc) * 1024 + (d & 31) * 16 + half * 8;
            *(u32x2*)(base + off) = lo;
            *(u32x2*)(base + off + 512) = hi;
        }
    }
}

// proj: fp32 out + bias
__global__ __launch_bounds__(256) void gemm_proj(const bf16* __restrict__ A,
                                                 const bf16* __restrict__ Bt,
                                                 const float* __restrict__ bias,
                                                 float* __restrict__ C) {
    __shared__ alignas(16) bf16 smem[6 * BM * BK];
    bf16* As = smem;
    bf16* Bs = smem + 3 * BM * BK;
    int wave = threadIdx.x >> 6, lane = threadIdx.x & 63;
    int wr = wave >> 1, wc = wave & 1;
    int m0 = blockIdx.y * BM, n0 = blockIdx.x * BN;
    f32x4 acc[4][4] = {};
    gemm_mainloop(A, Bt, EMB, m0, n0, As, Bs, wave, lane, wr, wc, acc);

    int m_base = m0 + wr * 64;
    int n_base = n0 + wc * 64;
#pragma unroll
    for (int i = 0; i < 4; i++) {
#pragma unroll
        for (int j = 0; j < 4; j++) {
            int col = n_base + j * 16 + (lane & 15);
            float bv = bias[col];
#pragma unroll
            for (int r = 0; r < 4; r++) {
                int row = m_base + i * 16 + 4 * (lane >> 4) + r;
                C[(size_t)row * EMB + col] = acc[i][j][r] + bv;
            }
        }
    }
}

// ---------------- attention (R17: T-group INTERLEAVED QK/exp/PV) ----------------
// 4 waves/block, 32 q-rows/wave, grid 512, 2 blocks/CU, KVBLK=128, K+V in LDS (dbuf).
// Per T-group: kf reads -> 4 QK MFMAs -> 16 exps -> the 4 PV MFMAs consuming w[T].
// Group T's PV MFMAs overlap group T+1's loads/QK/exp (MFMA||VALU co-issue).

__device__ __forceinline__ void stage16k(const bf16* src, bf16* lds, int wave, int lane) {
#pragma unroll
    for (int i = 0; i < 4; i++) {
        int c = wave * 4 + i;
        gload16(src + c * 512 + lane * 8, lds + c * 512);
    }
}

__device__ __forceinline__ u32 pack_bf16(float lo, float hi) {
    unsigned short a = __builtin_bit_cast(unsigned short, (bf16)lo);
    unsigned short b = __builtin_bit_cast(unsigned short, (bf16)hi);
    return (u32)a | ((u32)b << 16);
}

__global__ __launch_bounds__(256, 2) void attn(const bf16* __restrict__ Q,
                                               const bf16* __restrict__ K,
                                               const bf16* __restrict__ Vt,
                                               bf16* __restrict__ O) {
    // 512 blocks, 8 XCDs -> 64-block chunks = 4 bh per XCD
    int flat = blockIdx.x;
    int swz = (flat & 7) * 64 + (flat >> 3);
    int bh = swz >> 4;          // 16 q-blocks per bh
    int qb = swz & 15;

    int wave = threadIdx.x >> 6, lane = threadIdx.x & 63;
    int l31 = lane & 31, h = lane >> 5;
    int qw0 = qb * 128 + wave * 32;
    const bf16* Qg = Q + (size_t)bh * SEQ * DH;
    const bf16* Kg = K + (size_t)bh * SEQ * DH;
    const bf16* Vg = Vt + (size_t)bh * SEQ * DH;

    __shared__ alignas(16) bf16 Ks[2][8192];
    __shared__ alignas(16) bf16 Vs[2][8192];

    // Q B-fragments: qf[ks] = Q[qw0+l31][ks*16 + h*8 ..+7]
    bf16x8 qf[4];
#pragma unroll
    for (int ks = 0; ks < 4; ks++)
        qf[ks] = *(const bf16x8*)(Qg + (size_t)(qw0 + l31) * DH + ks * 16 + h * 8);

    f32x16 Oc[2] = {};
    float lsum = 0.f;

    stage16k(Kg, &Ks[0][0], wave, lane);
    stage16k(Vg, &Vs[0][0], wave, lane);
    asm volatile("s_waitcnt vmcnt(0)" ::: "memory");
    __builtin_amdgcn_s_barrier();

    int cur = 0;
    const int NIT = SEQ / 128;   // 16
    for (int it = 0; it < NIT; ++it) {
        if (it + 1 < NIT) {
            stage16k(Kg + (size_t)(it + 1) * 8192, &Ks[cur ^ 1][0], wave, lane);
            stage16k(Vg + (size_t)(it + 1) * 8192, &Vs[cur ^ 1][0], wave, lane);
        }
        const char* kc = (const char*)&Ks[cur][0];
        const char* vc = (const char*)&Vs[cur][0];

        float part[4];
#pragma unroll
        for (int T = 0; T < 4; T++) {
            // QK^T for row-group T
            bf16x8 kf[4];
#pragma unroll
            for (int ks = 0; ks < 4; ks++)
                kf[ks] = *(const bf16x8*)(kc + (((T * 4 + ks) * 2 + h) << 9) + l31 * 16);
            f32x16 st = {};
#pragma unroll
            for (int ks = 0; ks < 4; ks++)
                st = __builtin_amdgcn_mfma_f32_32x32x16_bf16(kf[ks], qf[ks], st, 0, 0, 0);

            // exp + pack (w for THIS group only)
            u32 w[8];
            float acc = 0.f;
#pragma unroll
            for (int p = 0; p < 8; p++) {
                float p0 = __expf(st[2 * p]);
                float p1 = __expf(st[2 * p + 1]);
                acc += p0 + p1;
                w[p] = pack_bf16(p0, p1);
            }
            part[T] = acc;

            // PV MFMAs consuming w[T]: mg = T>>1, mc in {2*(T&1), 2*(T&1)+1}
            int mg = T >> 1;
#pragma unroll
            for (int dt = 0; dt < 2; dt++)
#pragma unroll
                for (int mi = 0; mi < 2; mi++) {
                    int mc = 2 * (T & 1) + mi;
                    bf16x8 vf = *(const bf16x8*)(vc + mg * 8192 +
                                                 (((dt * 4 + mc) * 2 + h) << 9) + l31 * 16);
                    u32x4 pw = {w[4 * mi + 0], w[4 * mi + 1], w[4 * mi + 2], w[4 * mi + 3]};
                    bf16x8 pa = __builtin_bit_cast(bf16x8, pw);
                    Oc[dt] = __builtin_amdgcn_mfma_f32_32x32x16_bf16(pa, vf, Oc[dt], 0, 0, 0);
                }
        }
        lsum += (part[0] + part[1]) + (part[2] + part[3]);

        asm volatile("s_waitcnt vmcnt(0)" ::: "memory");
        __builtin_amdgcn_s_barrier();
        cur ^= 1;
    }

    // epilogue: denominator + scaled store
    float ls = lsum + __shfl_xor(lsum, 32);
    float rinv = 1.0f / ls;            // lane holds column q = l31
    int bb = bh >> 4, hh = bh & 15;
#pragma unroll
    for (int reg = 0; reg < 16; reg++) {
        int qlocal = (reg & 3) + 8 * (reg >> 2) + 4 * h;
        float sc = __shfl(rinv, qlocal);
        int row = qw0 + qlocal;
#pragma unroll
        for (int dt = 0; dt < 2; dt++) {
            O[((size_t)bb * SEQ + row) * EMB + hh * DH + dt * 32 + l31] =
                (bf16)(Oc[dt][reg] * sc);
        }
    }
}

// ---------------- launch ----------------

extern "C" void kernel_launch(void* const* d_in, const int* in_sizes, int n_in,
                              void* d_out, int out_size, void* d_ws, size_t ws_size,
                              hipStream_t stream) {
    const float* x     = (const float*)d_in[0];
    const float* Wqkv  = (const float*)d_in[1];
    const float* bqkv  = (const float*)d_in[2];
    const float* Wproj = (const float*)d_in[3];
    const float* bproj = (const float*)d_in[4];
    float* out = (float*)d_out;
    char* ws = (char*)d_ws;

    bf16* xb     = (bf16*)(ws + 0);          //  8 MB [4096][1024]
    bf16* attO   = xb;                       //  aliased: xb dead after gemm_qkv
    bf16* WqkvT  = (bf16*)(ws + 8388608);    //  6 MB [3072][1024] permuted
    bf16* WprojT = (bf16*)(ws + 14680064);   //  2 MB [1024][1024]
    bf16* Qb     = (bf16*)(ws + 16777216);   //  8 MB [32][2048][64] row-major
    bf16* Kb     = (bf16*)(ws + 25165824);   //  8 MB [32] chunked tiles
    bf16* Vt     = (bf16*)(ws + 33554432);   //  8 MB [32] chunked tiles

    prep<<<6144, 256, 0, stream>>>(x, xb, Wqkv, WqkvT, Wproj, WprojT);
    gemm_qkv<<<dim3(24, 32), 256, 0, stream>>>(xb, WqkvT, bqkv, Qb, Kb, Vt);
    attn<<<512, 256, 0, stream>>>(Qb, Kb, Vt, attO);
    gemm_proj<<<dim3(8, 32), 256, 0, stream>>>(attO, WprojT, bproj, out);
}